// Round 4
// baseline (1276.903 us; speedup 1.0000x reference)
//
#include <hip/hip_runtime.h>
#include <math.h>

#define Hh 256
#define Ww 256
#define HW 65536
#define Bn 4
#define Cdim 60
#define Ce 120
#define NPIX (Bn*HW)

typedef const float* fp;
typedef __attribute__((ext_vector_type(8))) float sf8;
typedef __attribute__((ext_vector_type(4))) float sf4;

// Pin a value into a VGPR: opaque asm result cannot be rematerialized, so the
// feeding load is issued exactly once and the value stays live in a register.
#define KEEP(x) asm volatile("" : "+v"(x))

__device__ __forceinline__ float gelu_exact(float x){
  return 0.5f*x*(1.f + erff(x*0.70710678118654752f));
}

__device__ __forceinline__ void tile_decode(int blk, int& b, int& h, int& tw){
  b = blk >> 10; int rem = blk & 1023; h = rem >> 2; tw = (rem & 3) << 6;
}

// Scalar-pipe weight loads: 32 floats (4x s_load_dwordx8) / 28 floats (3x x8 + 1x x4).
// waitcnt lives INSIDE the blob so consumers can't be hoisted past it (rule #18).
#define SLOAD32(P, W0, W1, W2, W3)                        \
  asm volatile("s_load_dwordx8 %0, %4, 0x0\n\t"           \
               "s_load_dwordx8 %1, %4, 0x20\n\t"          \
               "s_load_dwordx8 %2, %4, 0x40\n\t"          \
               "s_load_dwordx8 %3, %4, 0x60\n\t"          \
               "s_waitcnt lgkmcnt(0)"                     \
               : "=&s"(W0), "=&s"(W1), "=&s"(W2), "=&s"(W3) \
               : "s"(P))

#define SLOAD28(P, W4, W5, W6, WT)                        \
  asm volatile("s_load_dwordx8 %0, %4, 0x80\n\t"          \
               "s_load_dwordx8 %1, %4, 0xa0\n\t"          \
               "s_load_dwordx8 %2, %4, 0xc0\n\t"          \
               "s_load_dwordx4 %3, %4, 0xe0\n\t"          \
               "s_waitcnt lgkmcnt(0)"                     \
               : "=&s"(W4), "=&s"(W5), "=&s"(W6), "=&s"(WT) \
               : "s"(P))

// 60-term dot: W from SGPRs (scalar pipe), A from per-lane VGPRs. All indices static.
__device__ __forceinline__ float dot60(const float* __restrict__ wp, const float* A){
  sf8 w0_, w1_, w2_, w3_;
  SLOAD32(wp, w0_, w1_, w2_, w3_);
  float s0 = 0.f, s1 = 0.f, s2 = 0.f, s3 = 0.f;
  #pragma unroll
  for (int j = 0; j < 8; j++){
    s0 += w0_[j]*A[j];
    s1 += w1_[j]*A[8+j];
    s2 += w2_[j]*A[16+j];
    s3 += w3_[j]*A[24+j];
  }
  sf8 w4_, w5_, w6_; sf4 wt_;
  SLOAD28(wp, w4_, w5_, w6_, wt_);
  #pragma unroll
  for (int j = 0; j < 8; j++){
    s0 += w4_[j]*A[32+j];
    s1 += w5_[j]*A[40+j];
    s2 += w6_[j]*A[48+j];
  }
  #pragma unroll
  for (int j = 0; j < 4; j++)
    s3 += wt_[j]*A[56+j];
  return (s0 + s1) + (s2 + s3);
}

// ---------------- LFE stage 1: y1 = gelu(conv1x1(shift(src), w0, b0)) ----------------
// lane=pixel, wave=30-out group. A[60] pinned in VGPRs; one output at a time
// (dot60 -> gelu -> store), FULLY unrolled so no runtime-indexed arrays exist.
__global__ __launch_bounds__(256,4) void k_lfe1(const float* __restrict__ X, float* __restrict__ Y1,
                                                const float* __restrict__ w0,
                                                const float* __restrict__ b0){
  int tid = threadIdx.x;
  int lane = tid & 63;
  int wid  = __builtin_amdgcn_readfirstlane(tid >> 6);
  int b, h, tw; tile_decode(blockIdx.x, b, h, tw);
  const float* Xb = X + (size_t)b*(Cdim*HW);
  int ww0 = tw + lane;

  float A[60];
  #pragma unroll
  for (int k = 0; k < 60; k++){            // k static -> grp static
    int grp = k / 12;
    int hh = h, ww = ww0; bool ok = true;
    if (grp == 0){ ww += 1; ok = (ww < Ww); }
    else if (grp == 1){ ww -= 1; ok = (ww >= 0); }
    else if (grp == 2){ hh = h+1; ok = (hh < Hh); }
    else if (grp == 3){ hh = h-1; ok = (hh >= 0); }
    A[k] = ok ? Xb[(size_t)k*HW + hh*Ww + ww] : 0.f;
  }
  #pragma unroll
  for (int k = 0; k < 60; k++) KEEP(A[k]);

  const float* Wb = w0 + wid*(30*60);
  float* Yb = Y1 + (size_t)b*(Ce*HW) + h*Ww + tw + lane;
  #pragma unroll
  for (int oi = 0; oi < 30; oi++){         // FULL unroll: no acc array at all
    int o = wid*30 + oi;
    float s = dot60(Wb + oi*60, A) + b0[o];
    Yb[(size_t)o*HW] = gelu_exact(s);
  }
}

// ---------------- LFE stage 2: X = conv1x1(shift(y1), w1, b1) + resid ----------------
// K=120 in two 60-halves; acc[15] statically indexed (full unroll). sched_barrier
// between halves keeps the second half's A-loads from hoisting (live-set cap).
__global__ __launch_bounds__(256,4) void k_lfe2(const float* __restrict__ Y1,
                                                const float* __restrict__ R,
                                                float* __restrict__ X,
                                                const float* __restrict__ w1,
                                                const float* __restrict__ b1){
  int tid = threadIdx.x;
  int lane = tid & 63;
  int wid  = __builtin_amdgcn_readfirstlane(tid >> 6);
  int b, h, tw; tile_decode(blockIdx.x, b, h, tw);
  const float* Yb = Y1 + (size_t)b*(Ce*HW);
  int ww0 = tw + lane;

  float acc[15];
  #pragma unroll
  for (int oi = 0; oi < 15; oi++) acc[oi] = 0.f;
  const float* Wb = w1 + wid*(15*120);

  #pragma unroll
  for (int half = 0; half < 2; half++){    // full unroll: half static
    __builtin_amdgcn_sched_barrier(0);     // fence: don't hoist this half's loads
    float A[60];
    #pragma unroll
    for (int k = 0; k < 60; k++){
      int e = half*60 + k;                 // static
      int grp = e / 24;
      int hh = h, ww = ww0; bool ok = true;
      if (grp == 0){ ww += 1; ok = (ww < Ww); }
      else if (grp == 1){ ww -= 1; ok = (ww >= 0); }
      else if (grp == 2){ hh = h+1; ok = (hh < Hh); }
      else if (grp == 3){ hh = h-1; ok = (hh >= 0); }
      A[k] = ok ? Yb[(size_t)e*HW + hh*Ww + ww] : 0.f;
    }
    #pragma unroll
    for (int k = 0; k < 60; k++) KEEP(A[k]);
    #pragma unroll
    for (int oi = 0; oi < 15; oi++)
      acc[oi] += dot60(Wb + oi*120 + half*60, A);
  }

  const float* Rp = R + (size_t)b*(Cdim*HW) + h*Ww + tw + lane;
  float* Xp = X + (size_t)b*(Cdim*HW) + h*Ww + tw + lane;
  #pragma unroll
  for (int oi = 0; oi < 15; oi++){
    int o = wid*15 + oi;
    Xp[(size_t)o*HW] = acc[oi] + b1[o] + Rp[(size_t)o*HW];
  }
}

// ---------------- WSA stage 1: t = BN(conv1x1(x, pi_w, pi_b)) ----------------
__global__ __launch_bounds__(256,4) void k_wsat(const float* __restrict__ X, float* __restrict__ T,
                                                const float* __restrict__ piw,
                                                const float* __restrict__ pib,
                                                const float* __restrict__ g,
                                                const float* __restrict__ bt,
                                                const float* __restrict__ m,
                                                const float* __restrict__ v){
  int tid = threadIdx.x;
  int lane = tid & 63;
  int wid  = __builtin_amdgcn_readfirstlane(tid >> 6);
  int b, h, tw; tile_decode(blockIdx.x, b, h, tw);
  const float* Xb = X + (size_t)b*(Cdim*HW) + h*Ww + tw + lane;

  float A[60];
  #pragma unroll
  for (int k = 0; k < 60; k++)
    A[k] = Xb[(size_t)k*HW];
  #pragma unroll
  for (int k = 0; k < 60; k++) KEEP(A[k]);

  const float* Wb = piw + wid*(15*60);
  float* Tb = T + (size_t)b*(Cdim*HW) + h*Ww + tw + lane;
  #pragma unroll
  for (int oi = 0; oi < 15; oi++){         // full unroll, no acc array
    int o = wid*15 + oi;
    float s = dot60(Wb + oi*60, A);
    float scale = g[o] * rsqrtf(v[o] + 1e-5f);
    float cns   = (pib[o] - m[o])*scale + bt[o];
    Tb[(size_t)o*HW] = s*scale + cns;
  }
}

// ---------------- WSA stage 2: windowed attention (unchanged from round 3) ----------------
__global__ __launch_bounds__(256) void k_attn(const float* __restrict__ T, float* __restrict__ Y,
                                              fp mw, fp mb){
  __shared__ __align__(16) float R1[64*68]; // sub[k*68+p], later V[tok*68+c]
  __shared__ __align__(16) float R2[64*68]; // Wn[c*61+k] (mask_w), later St[q*68+p]
  __shared__ __align__(16) float R3[60*64]; // Qt[c*64+tok]; later softmax partials scratch
  int tid = threadIdx.x;
  int blk = blockIdx.x;
  int b = blk >> 10; int ij = blk & 1023; int wi = ij >> 5; int wj = ij & 31;
  const float* Tb = T + (size_t)b*(Cdim*HW);

  for (int idx = tid; idx < Cdim*64; idx += 256){
    int k = idx >> 6, p = idx & 63;
    int u = p >> 3, vq = p & 7;
    int r  = wi*8 + 2*vq; if (r > 255) r -= 8;
    int cc = wj*8 + 2*u;  if (cc > 255) cc -= 8;
    R1[k*68 + p] = Tb[k*HW + r*Ww + cc];
  }
  for (int idx = tid; idx < Cdim*Cdim; idx += 256){
    int c = idx / Cdim, k = idx - c*Cdim;
    R2[c*61 + k] = mw[idx];
  }
  __syncthreads();

  // qproj: q[p][c] = sum_k mw[c][k]*sub[k][p] + mb[c]
  if (tid < 240){
    int p0 = (tid & 15)*4, c0 = (tid >> 4)*4;
    float4 mb4 = *(const float4*)(mb + c0);
    float bias[4] = {mb4.x, mb4.y, mb4.z, mb4.w};
    float acc[4][4];
    #pragma unroll
    for (int ci = 0; ci < 4; ci++)
      #pragma unroll
      for (int pi = 0; pi < 4; pi++) acc[ci][pi] = bias[ci];
    #pragma unroll 4
    for (int k = 0; k < Cdim; k++){
      float4 a4 = *(const float4*)(&R1[k*68 + p0]);
      float av[4] = {a4.x, a4.y, a4.z, a4.w};
      #pragma unroll
      for (int ci = 0; ci < 4; ci++){
        float wv = R2[(c0+ci)*61 + k];
        #pragma unroll
        for (int pi = 0; pi < 4; pi++)
          acc[ci][pi] += wv*av[pi];
      }
    }
    #pragma unroll
    for (int ci = 0; ci < 4; ci++)
      *(float4*)(&R3[(c0+ci)*64 + p0]) = make_float4(acc[ci][0], acc[ci][1], acc[ci][2], acc[ci][3]);
  }
  __syncthreads();

  // stage V[tok][c] into R1 (sub dead); compute scores from R3
  {
    int p = tid & 63; int cg = tid >> 6;
    int pr = p >> 3, pc = p & 7;
    const float* base = Tb + (wi*8+pr)*Ww + (wj*8+pc);
    #pragma unroll
    for (int t2 = 0; t2 < 15; t2++)
      R1[p*68 + cg*15 + t2] = base[(cg*15+t2)*HW];
  }
  if (tid < 64){
    R1[tid*68 + 60] = 0.f; R1[tid*68 + 61] = 0.f;
    R1[tid*68 + 62] = 0.f; R1[tid*68 + 63] = 0.f;
  }
  {
    int p0 = (tid & 15)*4, q0 = (tid >> 4)*4;
    float acc[4][4];
    #pragma unroll
    for (int qi = 0; qi < 4; qi++)
      #pragma unroll
      for (int pi = 0; pi < 4; pi++) acc[qi][pi] = 0.f;
    #pragma unroll 4
    for (int c = 0; c < Cdim; c++){
      float4 A4 = *(const float4*)(&R3[c*64 + p0]);
      float4 B4 = *(const float4*)(&R3[c*64 + q0]);
      float Af[4] = {A4.x, A4.y, A4.z, A4.w};
      float Bf[4] = {B4.x, B4.y, B4.z, B4.w};
      #pragma unroll
      for (int qi = 0; qi < 4; qi++)
        #pragma unroll
        for (int pi = 0; pi < 4; pi++)
          acc[qi][pi] += Bf[qi]*Af[pi];
    }
    __syncthreads();   // qproj reads of R2/R3 done; V-stage R1 writes done
    #pragma unroll
    for (int qi = 0; qi < 4; qi++)
      *(float4*)(&R2[(q0+qi)*68 + p0]) = make_float4(acc[qi][0], acc[qi][1], acc[qi][2], acc[qi][3]);
  }
  __syncthreads();

  // parallel column softmax over q (all 256 threads): thread (g,p) owns 16 q's.
  {
    int p = tid & 63, gq = tid >> 6;
    float* Sc = R3;                       // Qt dead: [0..255] max partials, [256..511] sums
    float mx = -1e30f;
    #pragma unroll
    for (int i = 0; i < 16; i++) mx = fmaxf(mx, R2[(gq*16+i)*68 + p]);
    Sc[gq*64 + p] = mx;
    __syncthreads();
    float m0 = fmaxf(fmaxf(Sc[p], Sc[64+p]), fmaxf(Sc[128+p], Sc[192+p]));
    float sum = 0.f;
    #pragma unroll
    for (int i = 0; i < 16; i++){
      int q = gq*16 + i;
      float e = __expf(R2[q*68 + p] - m0);
      R2[q*68 + p] = e; sum += e;
    }
    Sc[256 + gq*64 + p] = sum;
    __syncthreads();
    float tot = (Sc[256+p] + Sc[320+p]) + (Sc[384+p] + Sc[448+p]);
    float inv = 1.f/tot;
    #pragma unroll
    for (int i = 0; i < 16; i++) R2[(gq*16+i)*68 + p] *= inv;
  }
  __syncthreads();

  {
    int p0 = (tid & 15)*4, c0 = (tid >> 4)*4;
    float acc[4][4];
    #pragma unroll
    for (int ci = 0; ci < 4; ci++)
      #pragma unroll
      for (int pi = 0; pi < 4; pi++) acc[ci][pi] = 0.f;
    #pragma unroll 4
    for (int q = 0; q < 64; q++){
      float4 S4 = *(const float4*)(&R2[q*68 + p0]);
      float4 V4 = *(const float4*)(&R1[q*68 + c0]);
      float Sf[4] = {S4.x, S4.y, S4.z, S4.w};
      float Vf[4] = {V4.x, V4.y, V4.z, V4.w};
      #pragma unroll
      for (int ci = 0; ci < 4; ci++)
        #pragma unroll
        for (int pi = 0; pi < 4; pi++)
          acc[ci][pi] += Sf[pi]*Vf[ci];
    }
    float* Yb = Y + (size_t)b*(Cdim*HW);
    #pragma unroll
    for (int ci = 0; ci < 4; ci++){
      int c = c0 + ci;
      if (c < Cdim){
        #pragma unroll
        for (int pi = 0; pi < 4; pi++){
          int p = p0 + pi;
          Yb[c*HW + (wi*8 + (p>>3))*Ww + wj*8 + (p&7)] = acc[ci][pi];
        }
      }
    }
  }
}

// ---------------- WSA stage 3: X = conv1x1(y, po) + X ----------------
__global__ __launch_bounds__(256,4) void k_wsaout(const float* __restrict__ Y, float* __restrict__ X,
                                                  const float* __restrict__ pw,
                                                  const float* __restrict__ pb){
  int tid = threadIdx.x;
  int lane = tid & 63;
  int wid  = __builtin_amdgcn_readfirstlane(tid >> 6);
  int b, h, tw; tile_decode(blockIdx.x, b, h, tw);
  const float* Yb = Y + (size_t)b*(Cdim*HW) + h*Ww + tw + lane;

  float A[60];
  #pragma unroll
  for (int k = 0; k < 60; k++)
    A[k] = Yb[(size_t)k*HW];
  #pragma unroll
  for (int k = 0; k < 60; k++) KEEP(A[k]);

  const float* Wb = pw + wid*(15*60);
  float* Xp = X + (size_t)b*(Cdim*HW) + h*Ww + tw + lane;
  #pragma unroll
  for (int oi = 0; oi < 15; oi++){         // full unroll, no acc array
    int o = wid*15 + oi;
    float s = dot60(Wb + oi*60, A);
    Xp[(size_t)o*HW] = s + pb[o] + Xp[(size_t)o*HW];
  }
}

extern "C" void kernel_launch(void* const* d_in, const int* in_sizes, int n_in,
                              void* d_out, int out_size, void* d_ws, size_t ws_size,
                              hipStream_t stream){
  fp x      = (fp)d_in[0];
  fp lfe_w0 = (fp)d_in[1];
  fp lfe_b0 = (fp)d_in[2];
  fp lfe_w1 = (fp)d_in[3];
  fp lfe_b1 = (fp)d_in[4];
  fp pi_w   = (fp)d_in[5];
  fp pi_b   = (fp)d_in[6];
  fp bn_g   = (fp)d_in[7];
  fp bn_b   = (fp)d_in[8];
  fp bn_m   = (fp)d_in[9];
  fp bn_v   = (fp)d_in[10];
  fp mask_w = (fp)d_in[11];
  fp mask_b = (fp)d_in[12];
  fp po_w   = (fp)d_in[13];
  fp po_b   = (fp)d_in[14];

  const size_t XSZ = (size_t)Bn*Cdim*HW;     // 15,728,640 floats (63 MB)
  float* X  = (float*)d_out;                 // residual stream lives in d_out (fp32)
  float* Y1 = (float*)d_ws;                  // [0, 2*XSZ): 120-ch LFE intermediate
  float* T  = Y1;                            // [0, XSZ): t-tensor (Y1 dead by then)
  float* Yw = Y1 + XSZ;                      // [XSZ, 2*XSZ): attention output

  const int NT = NPIX/64;                    // 4096 64-px tiles

  for (int d = 0; d < 2; d++){
    fp src = (d == 0) ? x : X;               // depth-0 reads the input directly
    k_lfe1  <<<NT, 256, 0, stream>>>(src, Y1, lfe_w0 + d*Ce*Cdim, lfe_b0 + d*Ce);
    k_lfe2  <<<NT, 256, 0, stream>>>(Y1, src, X, lfe_w1 + d*Ce*Cdim, lfe_b1 + d*Cdim);
    k_wsat  <<<NT, 256, 0, stream>>>(X, T, pi_w + d*Cdim*Cdim, pi_b + d*Cdim,
                                     bn_g + d*Cdim, bn_b + d*Cdim, bn_m + d*Cdim, bn_v + d*Cdim);
    k_attn  <<<Bn*32*32, 256, 0, stream>>>(T, Yw, mask_w + d*Cdim*Cdim, mask_b + d*Cdim);
    k_wsaout<<<NT, 256, 0, stream>>>(Yw, X, po_w + d*Cdim*Cdim, po_b + d*Cdim);
  }
}

// Round 5
// 1059.593 us; speedup vs baseline: 1.2051x; 1.2051x over previous
//
#include <hip/hip_runtime.h>
#include <math.h>

#define Hh 256
#define Ww 256
#define HW 65536
#define Bn 4
#define Cdim 60
#define Ce 120
#define NPIX (Bn*HW)

typedef const float* fp;

__device__ __forceinline__ float gelu_exact(float x){
  return 0.5f*x*(1.f + erff(x*0.70710678118654752f));
}

// decode 64-px tile id -> (b, h, tw). 1024 tiles/image (256 rows x 4 tiles).
__device__ __forceinline__ void tile_decode(int blk, int& b, int& h, int& tw){
  b = blk >> 10; int rem = blk & 1023; h = rem >> 2; tw = (rem & 3) << 6;
}

// ---------------- LFE stage 1: y1 = gelu(conv1x1(shift(src), w0, b0)) ----------------
// GEMM: M=64 px, N=120 out, K=60. W staged TRANSPOSED [k][o] stride 132 so the
// 8 per-k W broadcasts become 2 conflict-free ds_read_b128 (banks (4k+o0)%32,
// o0 in {0,8,16,24} -> disjoint quads). A read via b128 as before.
__global__ __launch_bounds__(256) void k_lfe1(const float* __restrict__ X, float* __restrict__ Y1,
                                              fp w0, fp b0){
  __shared__ __align__(16) float A[60*64];     // shifted input [k][p]
  __shared__ __align__(16) float Wt[60*132];   // transposed weights [k][o], stride 132
  int tid = threadIdx.x;
  int b, h, tw; tile_decode(blockIdx.x, b, h, tw);
  const float* Xb = X + (size_t)b*(Cdim*HW);
  for (int idx = tid; idx < 60*64; idx += 256){
    int k = idx >> 6, p = idx & 63;
    int grp = k / 12;
    int hh = h, ww = tw + p; bool ok = true;
    if (grp == 0){ ww += 1; ok = (ww < Ww); }
    else if (grp == 1){ ww -= 1; ok = (ww >= 0); }
    else if (grp == 2){ hh = h+1; ok = (hh < Hh); }
    else if (grp == 3){ hh = h-1; ok = (hh >= 0); }
    A[idx] = ok ? Xb[k*HW + hh*Ww + ww] : 0.f;
  }
  for (int idx = tid; idx < 120*60; idx += 256){   // coalesced read; transposed write
    int o = idx / 60, k = idx - o*60;
    Wt[k*132 + o] = w0[idx];
  }
  __syncthreads();
  if (tid < 240){
    int p0 = (tid & 15)*4;
    int o0 = (tid >> 4)*8;
    float acc[8][4];
    #pragma unroll
    for (int oi = 0; oi < 8; oi++){
      float bb = b0[o0+oi];
      #pragma unroll
      for (int pi = 0; pi < 4; pi++) acc[oi][pi] = bb;
    }
    #pragma unroll 4
    for (int k = 0; k < 60; k++){
      float4 a4 = *(const float4*)(&A[k*64 + p0]);
      float av[4] = {a4.x,a4.y,a4.z,a4.w};
      float4 wa = *(const float4*)(&Wt[k*132 + o0]);
      float4 wb = *(const float4*)(&Wt[k*132 + o0 + 4]);
      float wv[8] = {wa.x,wa.y,wa.z,wa.w, wb.x,wb.y,wb.z,wb.w};
      #pragma unroll
      for (int oi = 0; oi < 8; oi++){
        #pragma unroll
        for (int pi = 0; pi < 4; pi++)
          acc[oi][pi] += wv[oi]*av[pi];
      }
    }
    float* Yb = Y1 + (size_t)b*(Ce*HW) + h*Ww + tw + p0;
    #pragma unroll
    for (int oi = 0; oi < 8; oi++){
      float4 r;
      r.x = gelu_exact(acc[oi][0]); r.y = gelu_exact(acc[oi][1]);
      r.z = gelu_exact(acc[oi][2]); r.w = gelu_exact(acc[oi][3]);
      *(float4*)(Yb + (size_t)(o0+oi)*HW) = r;
    }
  }
}

// ---------------- LFE stage 2: X = conv1x1(shift(y1), w1, b1) + resid ----------------
// GEMM: M=64, N=60, K=120 (A staged in two 60-row halves). W transposed [e][c] stride 68:
// per k one conflict-free b128 (o0 in {0,4,8,12} -> banks (4e+o0)%32 disjoint).
__global__ __launch_bounds__(256) void k_lfe2(const float* __restrict__ Y1,
                                              const float* __restrict__ R,
                                              float* __restrict__ X,
                                              fp w1, fp b1){
  __shared__ __align__(16) float A[60*64];
  __shared__ __align__(16) float Wt[120*68];   // transposed [e][c], stride 68
  int tid = threadIdx.x;
  int b, h, tw; tile_decode(blockIdx.x, b, h, tw);
  const float* Yb = Y1 + (size_t)b*(Ce*HW);
  for (int idx = tid; idx < 60*120; idx += 256){
    int c = idx / 120, e = idx - c*120;
    Wt[e*68 + c] = w1[idx];
  }
  int p0 = (tid & 15)*4;
  int o0 = (tid >> 4)*4;
  float acc[4][4];
  #pragma unroll
  for (int oi = 0; oi < 4; oi++)
    #pragma unroll
    for (int pi = 0; pi < 4; pi++) acc[oi][pi] = 0.f;
  #pragma unroll 1
  for (int half = 0; half < 2; half++){
    __syncthreads();                            // W ready / previous half's GEMM reads done
    for (int idx = tid; idx < 60*64; idx += 256){
      int k = idx >> 6, p = idx & 63;
      int e = half*60 + k;
      int grp = e / 24;
      int hh = h, ww = tw + p; bool ok = true;
      if (grp == 0){ ww += 1; ok = (ww < Ww); }
      else if (grp == 1){ ww -= 1; ok = (ww >= 0); }
      else if (grp == 2){ hh = h+1; ok = (hh < Hh); }
      else if (grp == 3){ hh = h-1; ok = (hh >= 0); }
      A[idx] = ok ? Yb[e*HW + hh*Ww + ww] : 0.f;
    }
    __syncthreads();
    if (tid < 240){
      #pragma unroll 4
      for (int k = 0; k < 60; k++){
        float4 a4 = *(const float4*)(&A[k*64 + p0]);
        float av[4] = {a4.x,a4.y,a4.z,a4.w};
        float4 w4 = *(const float4*)(&Wt[(half*60 + k)*68 + o0]);
        float wv[4] = {w4.x,w4.y,w4.z,w4.w};
        #pragma unroll
        for (int oi = 0; oi < 4; oi++){
          #pragma unroll
          for (int pi = 0; pi < 4; pi++)
            acc[oi][pi] += wv[oi]*av[pi];
        }
      }
    }
  }
  if (tid < 240){
    const float* Rp = R + (size_t)b*(Cdim*HW) + h*Ww + tw + p0;
    float* Xp = X + (size_t)b*(Cdim*HW) + h*Ww + tw + p0;
    #pragma unroll
    for (int oi = 0; oi < 4; oi++){
      int o = o0 + oi;
      float bb = b1[o];
      float4 r4 = *(const float4*)(Rp + (size_t)o*HW);
      float4 out;
      out.x = acc[oi][0] + bb + r4.x;
      out.y = acc[oi][1] + bb + r4.y;
      out.z = acc[oi][2] + bb + r4.z;
      out.w = acc[oi][3] + bb + r4.w;
      *(float4*)(Xp + (size_t)o*HW) = out;
    }
  }
}

// ---------------- WSA stage 1: t = BN(conv1x1(x, pi_w, pi_b)) ----------------
// GEMM: M=64, N=60, K=60. W transposed [k][o] stride 68 with BN scale folded at staging.
__global__ __launch_bounds__(256) void k_wsat(const float* __restrict__ X, float* __restrict__ T,
                                              fp piw, fp pib, fp g, fp bt, fp m, fp v){
  __shared__ __align__(16) float A[60*64];
  __shared__ __align__(16) float Wt[60*68];
  int tid = threadIdx.x;
  int b, h, tw; tile_decode(blockIdx.x, b, h, tw);
  const float* Xb = X + (size_t)b*(Cdim*HW) + h*Ww + tw;
  for (int idx = tid; idx < 60*64; idx += 256){
    int k = idx >> 6, p = idx & 63;
    A[idx] = Xb[k*HW + p];
  }
  for (int idx = tid; idx < 60*60; idx += 256){
    int o = idx / 60, k = idx - o*60;
    float scale = g[o] * rsqrtf(v[o] + 1e-5f);
    Wt[k*68 + o] = piw[idx] * scale;
  }
  __syncthreads();
  if (tid < 240){
    int p0 = (tid & 15)*4;
    int o0 = (tid >> 4)*4;
    float acc[4][4];
    #pragma unroll
    for (int oi = 0; oi < 4; oi++)
      #pragma unroll
      for (int pi = 0; pi < 4; pi++) acc[oi][pi] = 0.f;
    #pragma unroll 4
    for (int k = 0; k < 60; k++){
      float4 a4 = *(const float4*)(&A[k*64 + p0]);
      float av[4] = {a4.x,a4.y,a4.z,a4.w};
      float4 w4 = *(const float4*)(&Wt[k*68 + o0]);
      float wv[4] = {w4.x,w4.y,w4.z,w4.w};
      #pragma unroll
      for (int oi = 0; oi < 4; oi++){
        #pragma unroll
        for (int pi = 0; pi < 4; pi++)
          acc[oi][pi] += wv[oi]*av[pi];
      }
    }
    float* Tb = T + (size_t)b*(Cdim*HW) + h*Ww + tw + p0;
    #pragma unroll
    for (int oi = 0; oi < 4; oi++){
      int o = o0 + oi;
      float scale = g[o] * rsqrtf(v[o] + 1e-5f);
      float cns   = (pib[o] - m[o])*scale + bt[o];
      float4 out;
      out.x = acc[oi][0] + cns;
      out.y = acc[oi][1] + cns;
      out.z = acc[oi][2] + cns;
      out.w = acc[oi][3] + cns;
      *(float4*)(Tb + (size_t)o*HW) = out;
    }
  }
}

// ---------------- WSA stage 2: windowed attention (parallel softmax) ----------------
// mask_w staged NATURAL [c][k] pad-61 into R2 (overwritten by scores after barrier).
__global__ __launch_bounds__(256) void k_attn(const float* __restrict__ T, float* __restrict__ Y,
                                              fp mw, fp mb){
  __shared__ __align__(16) float R1[64*68]; // sub[k*68+p], later V[tok*68+c]
  __shared__ __align__(16) float R2[64*68]; // Wn[c*61+k] (mask_w), later St[q*68+p]
  __shared__ __align__(16) float R3[60*64]; // Qt[c*64+tok]; later softmax partials scratch
  int tid = threadIdx.x;
  int blk = blockIdx.x;
  int b = blk >> 10; int ij = blk & 1023; int wi = ij >> 5; int wj = ij & 31;
  const float* Tb = T + (size_t)b*(Cdim*HW);

  for (int idx = tid; idx < Cdim*64; idx += 256){
    int k = idx >> 6, p = idx & 63;
    int u = p >> 3, vq = p & 7;
    int r  = wi*8 + 2*vq; if (r > 255) r -= 8;
    int cc = wj*8 + 2*u;  if (cc > 255) cc -= 8;
    R1[k*68 + p] = Tb[k*HW + r*Ww + cc];
  }
  for (int idx = tid; idx < Cdim*Cdim; idx += 256){   // coalesced, natural layout
    int c = idx / Cdim, k = idx - c*Cdim;
    R2[c*61 + k] = mw[idx];
  }
  __syncthreads();

  // qproj: q[p][c] = sum_k mw[c][k]*sub[k][p] + mb[c]
  if (tid < 240){
    int p0 = (tid & 15)*4, c0 = (tid >> 4)*4;
    float4 mb4 = *(const float4*)(mb + c0);
    float bias[4] = {mb4.x, mb4.y, mb4.z, mb4.w};
    float acc[4][4];
    #pragma unroll
    for (int ci = 0; ci < 4; ci++)
      #pragma unroll
      for (int pi = 0; pi < 4; pi++) acc[ci][pi] = bias[ci];
    #pragma unroll 4
    for (int k = 0; k < Cdim; k++){
      float4 a4 = *(const float4*)(&R1[k*68 + p0]);
      float av[4] = {a4.x, a4.y, a4.z, a4.w};
      #pragma unroll
      for (int ci = 0; ci < 4; ci++){
        float wv = R2[(c0+ci)*61 + k];
        #pragma unroll
        for (int pi = 0; pi < 4; pi++)
          acc[ci][pi] += wv*av[pi];
      }
    }
    #pragma unroll
    for (int ci = 0; ci < 4; ci++)
      *(float4*)(&R3[(c0+ci)*64 + p0]) = make_float4(acc[ci][0], acc[ci][1], acc[ci][2], acc[ci][3]);
  }
  __syncthreads();

  // stage V[tok][c] into R1 (sub dead); compute scores from R3
  {
    int p = tid & 63; int cg = tid >> 6;
    int pr = p >> 3, pc = p & 7;
    const float* base = Tb + (wi*8+pr)*Ww + (wj*8+pc);
    #pragma unroll
    for (int t2 = 0; t2 < 15; t2++)
      R1[p*68 + cg*15 + t2] = base[(cg*15+t2)*HW];
  }
  if (tid < 64){
    R1[tid*68 + 60] = 0.f; R1[tid*68 + 61] = 0.f;
    R1[tid*68 + 62] = 0.f; R1[tid*68 + 63] = 0.f;
  }
  {
    int p0 = (tid & 15)*4, q0 = (tid >> 4)*4;
    float acc[4][4];
    #pragma unroll
    for (int qi = 0; qi < 4; qi++)
      #pragma unroll
      for (int pi = 0; pi < 4; pi++) acc[qi][pi] = 0.f;
    #pragma unroll 4
    for (int c = 0; c < Cdim; c++){
      float4 A4 = *(const float4*)(&R3[c*64 + p0]);
      float4 B4 = *(const float4*)(&R3[c*64 + q0]);
      float Af[4] = {A4.x, A4.y, A4.z, A4.w};
      float Bf[4] = {B4.x, B4.y, B4.z, B4.w};
      #pragma unroll
      for (int qi = 0; qi < 4; qi++)
        #pragma unroll
        for (int pi = 0; pi < 4; pi++)
          acc[qi][pi] += Bf[qi]*Af[pi];
    }
    __syncthreads();   // qproj reads of R2/R3 done; V-stage R1 writes done
    #pragma unroll
    for (int qi = 0; qi < 4; qi++)
      *(float4*)(&R2[(q0+qi)*68 + p0]) = make_float4(acc[qi][0], acc[qi][1], acc[qi][2], acc[qi][3]);
  }
  __syncthreads();

  // parallel column softmax over q (all 256 threads): thread (gq,p) owns 16 q's.
  {
    int p = tid & 63, gq = tid >> 6;
    float* Sc = R3;                       // Qt dead: [0..255] max partials, [256..511] sums
    float mx = -1e30f;
    #pragma unroll
    for (int i = 0; i < 16; i++) mx = fmaxf(mx, R2[(gq*16+i)*68 + p]);
    Sc[gq*64 + p] = mx;
    __syncthreads();
    float m0 = fmaxf(fmaxf(Sc[p], Sc[64+p]), fmaxf(Sc[128+p], Sc[192+p]));
    float sum = 0.f;
    #pragma unroll
    for (int i = 0; i < 16; i++){
      int q = gq*16 + i;
      float e = __expf(R2[q*68 + p] - m0);
      R2[q*68 + p] = e; sum += e;
    }
    Sc[256 + gq*64 + p] = sum;
    __syncthreads();
    float tot = (Sc[256+p] + Sc[320+p]) + (Sc[384+p] + Sc[448+p]);
    float inv = 1.f/tot;
    #pragma unroll
    for (int i = 0; i < 16; i++) R2[(gq*16+i)*68 + p] *= inv;
  }
  __syncthreads();

  {
    int p0 = (tid & 15)*4, c0 = (tid >> 4)*4;
    float acc[4][4];
    #pragma unroll
    for (int ci = 0; ci < 4; ci++)
      #pragma unroll
      for (int pi = 0; pi < 4; pi++) acc[ci][pi] = 0.f;
    #pragma unroll 4
    for (int q = 0; q < 64; q++){
      float4 S4 = *(const float4*)(&R2[q*68 + p0]);
      float4 V4 = *(const float4*)(&R1[q*68 + c0]);
      float Sf[4] = {S4.x, S4.y, S4.z, S4.w};
      float Vf[4] = {V4.x, V4.y, V4.z, V4.w};
      #pragma unroll
      for (int ci = 0; ci < 4; ci++)
        #pragma unroll
        for (int pi = 0; pi < 4; pi++)
          acc[ci][pi] += Sf[pi]*Vf[ci];
    }
    float* Yb = Y + (size_t)b*(Cdim*HW);
    #pragma unroll
    for (int ci = 0; ci < 4; ci++){
      int c = c0 + ci;
      if (c < Cdim){
        #pragma unroll
        for (int pi = 0; pi < 4; pi++){
          int p = p0 + pi;
          Yb[c*HW + (wi*8 + (p>>3))*Ww + wj*8 + (p&7)] = acc[ci][pi];
        }
      }
    }
  }
}

// ---------------- WSA stage 3: X = conv1x1(y, po) + X ----------------
__global__ __launch_bounds__(256) void k_wsaout(const float* __restrict__ Y, float* __restrict__ X,
                                                fp pw, fp pb){
  __shared__ __align__(16) float A[60*64];
  __shared__ __align__(16) float Wt[60*68];
  int tid = threadIdx.x;
  int b, h, tw; tile_decode(blockIdx.x, b, h, tw);
  const float* Yb = Y + (size_t)b*(Cdim*HW) + h*Ww + tw;
  for (int idx = tid; idx < 60*64; idx += 256){
    int k = idx >> 6, p = idx & 63;
    A[idx] = Yb[k*HW + p];
  }
  for (int idx = tid; idx < 60*60; idx += 256){
    int o = idx / 60, k = idx - o*60;
    Wt[k*68 + o] = pw[idx];
  }
  __syncthreads();
  if (tid < 240){
    int p0 = (tid & 15)*4;
    int o0 = (tid >> 4)*4;
    float acc[4][4];
    #pragma unroll
    for (int oi = 0; oi < 4; oi++)
      #pragma unroll
      for (int pi = 0; pi < 4; pi++) acc[oi][pi] = 0.f;
    #pragma unroll 4
    for (int k = 0; k < 60; k++){
      float4 a4 = *(const float4*)(&A[k*64 + p0]);
      float av[4] = {a4.x,a4.y,a4.z,a4.w};
      float4 w4 = *(const float4*)(&Wt[k*68 + o0]);
      float wv[4] = {w4.x,w4.y,w4.z,w4.w};
      #pragma unroll
      for (int oi = 0; oi < 4; oi++){
        #pragma unroll
        for (int pi = 0; pi < 4; pi++)
          acc[oi][pi] += wv[oi]*av[pi];
      }
    }
    float* Xp = X + (size_t)b*(Cdim*HW) + h*Ww + tw + p0;
    #pragma unroll
    for (int oi = 0; oi < 4; oi++){
      int o = o0 + oi;
      float bb = pb[o];
      float4 r4 = *(const float4*)(Xp + (size_t)o*HW);
      float4 out;
      out.x = acc[oi][0] + bb + r4.x;
      out.y = acc[oi][1] + bb + r4.y;
      out.z = acc[oi][2] + bb + r4.z;
      out.w = acc[oi][3] + bb + r4.w;
      *(float4*)(Xp + (size_t)o*HW) = out;
    }
  }
}

extern "C" void kernel_launch(void* const* d_in, const int* in_sizes, int n_in,
                              void* d_out, int out_size, void* d_ws, size_t ws_size,
                              hipStream_t stream){
  fp x      = (fp)d_in[0];
  fp lfe_w0 = (fp)d_in[1];
  fp lfe_b0 = (fp)d_in[2];
  fp lfe_w1 = (fp)d_in[3];
  fp lfe_b1 = (fp)d_in[4];
  fp pi_w   = (fp)d_in[5];
  fp pi_b   = (fp)d_in[6];
  fp bn_g   = (fp)d_in[7];
  fp bn_b   = (fp)d_in[8];
  fp bn_m   = (fp)d_in[9];
  fp bn_v   = (fp)d_in[10];
  fp mask_w = (fp)d_in[11];
  fp mask_b = (fp)d_in[12];
  fp po_w   = (fp)d_in[13];
  fp po_b   = (fp)d_in[14];

  const size_t XSZ = (size_t)Bn*Cdim*HW;     // 15,728,640 floats (63 MB)
  float* X  = (float*)d_out;                 // residual stream lives in d_out (fp32)
  float* Y1 = (float*)d_ws;                  // [0, 2*XSZ): 120-ch LFE intermediate
  float* T  = Y1;                            // [0, XSZ): t-tensor (Y1 dead by then)
  float* Yw = Y1 + XSZ;                      // [XSZ, 2*XSZ): attention output

  const int NT = NPIX/64;                    // 4096 64-px tiles

  for (int d = 0; d < 2; d++){
    fp src = (d == 0) ? x : X;               // depth-0 reads the input directly
    k_lfe1  <<<NT, 256, 0, stream>>>(src, Y1, lfe_w0 + d*Ce*Cdim, lfe_b0 + d*Ce);
    k_lfe2  <<<NT, 256, 0, stream>>>(Y1, src, X, lfe_w1 + d*Ce*Cdim, lfe_b1 + d*Cdim);
    k_wsat  <<<NT, 256, 0, stream>>>(X, T, pi_w + d*Cdim*Cdim, pi_b + d*Cdim,
                                     bn_g + d*Cdim, bn_b + d*Cdim, bn_m + d*Cdim, bn_v + d*Cdim);
    k_attn  <<<Bn*32*32, 256, 0, stream>>>(T, Yw, mask_w + d*Cdim*Cdim, mask_b + d*Cdim);
    k_wsaout<<<NT, 256, 0, stream>>>(Yw, X, po_w + d*Cdim*Cdim, po_b + d*Cdim);
  }
}